// Round 7
// baseline (92.282 us; speedup 1.0000x reference)
//
#include <hip/hip_runtime.h>
#include <math.h>

#define HWPIX 3136   // 56*56
#define NC    256
#define NCNEW 128
#define NH    16     // C/R

// ---------------------------------------------------------------------------
// INSTRUMENTATION ROUND: the round-6 pipeline launched TWICE back-to-back.
// All kernels are idempotent & deterministic, so output is bit-identical.
// T2 - T1 = sum(kernel durations) + 3*gap  -> separates in-kernel time from
// fixed per-replay overhead, which 3 rounds of theory failed to localize.
// ---------------------------------------------------------------------------

// numpy pairwise block sum (8 <= n <= 128) — exact np order.
__device__ __forceinline__ float np_block_sum(const float* __restrict__ a, int n) {
    float r0=a[0],r1=a[1],r2=a[2],r3=a[3],r4=a[4],r5=a[5],r6=a[6],r7=a[7];
    int i = 8;
    const int lim = n - (n & 7);
    for (; i < lim; i += 8) {
        r0 += a[i+0]; r1 += a[i+1]; r2 += a[i+2]; r3 += a[i+3];
        r4 += a[i+4]; r5 += a[i+5]; r6 += a[i+6]; r7 += a[i+7];
    }
    float res = ((r0 + r1) + (r2 + r3)) + ((r4 + r5) + (r6 + r7));
    for (; i < n; ++i) res += a[i];
    return res;
}

__global__ __launch_bounds__(64) void k_mean(const float* __restrict__ x,
                                             float* __restrict__ s) {
    const int plane = blockIdx.x;  // b*256 + c
    const int t = threadIdx.x;
    __shared__ float pl[HWPIX];

    const float4* src4 = reinterpret_cast<const float4*>(x + (size_t)plane * HWPIX);

    float4 va[13];
    #pragma unroll
    for (int i = 0; i < 12; ++i) va[i] = src4[i * 64 + t];
    {   int idx = 768 + t; if (idx > 783) idx = 783;
        va[12] = src4[idx];
    }
    #pragma unroll
    for (int i = 0; i < 12; ++i)
        *reinterpret_cast<float4*>(&pl[(i * 64 + t) * 4]) = va[i];
    if (t < 16)
        *reinterpret_cast<float4*>(&pl[(768 + t) * 4]) = va[12];
    __syncthreads();

    const int m    = t >> 1;
    const int base = 98 * m + ((t & 1) ? 48 : 0);
    const int n    = (t & 1) ? 50 : 48;
    float v = np_block_sum(pl + base, n);

    #pragma unroll
    for (int mask = 1; mask <= 32; mask <<= 1)
        v += __shfl_xor(v, mask, 64);

    if (t == 0) s[plane] = v / 3136.0f;
}

__global__ __launch_bounds__(256) void k_mlp_topk(const float* __restrict__ s,
                                                  const float* __restrict__ w1,
                                                  const float* __restrict__ b1,
                                                  const float* __restrict__ w2,
                                                  const float* __restrict__ b2,
                                                  float* __restrict__ gate_out,
                                                  int* __restrict__ idx_out) {
    const int b   = blockIdx.x;
    const int tid = threadIdx.x;

    __shared__ float sh_s[NC];
    __shared__ float sh_w1t[NC][NH];
    __shared__ float sh_w2[NC * NH];
    __shared__ float sh_h[NH];
    __shared__ float sh_g[NC];

    const float bias2 = b2[tid];
    float bias1 = 0.0f;
    if (tid < NH) bias1 = b1[tid];

    #pragma unroll
    for (int i = 0; i < 4; ++i) {
        const int f4 = i * 256 + tid;
        float4 v = reinterpret_cast<const float4*>(w1)[f4];
        const int base = f4 * 4;
        const int j = base >> 8;
        const int k = base & 255;
        sh_w1t[k+0][j] = v.x; sh_w1t[k+1][j] = v.y;
        sh_w1t[k+2][j] = v.z; sh_w1t[k+3][j] = v.w;
        reinterpret_cast<float4*>(sh_w2)[f4] =
            reinterpret_cast<const float4*>(w2)[f4];
    }
    if (tid < 64)
        reinterpret_cast<float4*>(sh_s)[tid] =
            reinterpret_cast<const float4*>(s + b * NC)[tid];
    __syncthreads();

    if (tid < NH) {
        float acc = 0.0f;
        #pragma unroll 16
        for (int k = 0; k < NC; ++k)
            acc = fmaf(sh_s[k], sh_w1t[k][tid], acc);
        float hp = acc + bias1;
        sh_h[tid] = fmaxf(hp, 0.0f);
    }
    __syncthreads();

    float acc = 0.0f;
    #pragma unroll
    for (int j = 0; j < NH; ++j)
        acc = fmaf(sh_h[j], sh_w2[tid * NH + j], acc);
    const float z  = acc + bias2;
    const float ef = (float)exp((double)(-z));
    const float g  = 1.0f / (1.0f + ef);
    sh_g[tid] = g;
    __syncthreads();

    int r = 0;
    #pragma unroll 8
    for (int k = 0; k < NC; ++k) {
        const float gk = sh_g[k];
        r += (gk > g) || (gk == g && k < tid);
    }
    if (r < NCNEW) {
        gate_out[b * NCNEW + r] = g;
        idx_out[b * NCNEW + r]  = tid;
    }
}

__global__ __launch_bounds__(256) void k_gather(const float* __restrict__ x,
                                                const float* __restrict__ gate,
                                                const int* __restrict__ idx,
                                                float* __restrict__ out) {
    const int bid = blockIdx.x;      // b*128 + j
    const int b = bid >> 7;
    const int c = idx[bid];
    const float g = gate[bid];

    const float4* src = reinterpret_cast<const float4*>(
        x + ((size_t)(b * NC + c)) * HWPIX);
    float4* dst = reinterpret_cast<float4*>(out + (size_t)bid * HWPIX);

    const int t = threadIdx.x;
    float4 v;
    v = src[t];       v.x *= g; v.y *= g; v.z *= g; v.w *= g; dst[t]       = v;
    v = src[t + 256]; v.x *= g; v.y *= g; v.z *= g; v.w *= g; dst[t + 256] = v;
    v = src[t + 512]; v.x *= g; v.y *= g; v.z *= g; v.w *= g; dst[t + 512] = v;
    if (t < 16) {
        v = src[t + 768]; v.x *= g; v.y *= g; v.z *= g; v.w *= g; dst[t + 768] = v;
    }
}

extern "C" void kernel_launch(void* const* d_in, const int* in_sizes, int n_in,
                              void* d_out, int out_size, void* d_ws, size_t ws_size,
                              hipStream_t stream) {
    const float* x  = (const float*)d_in[0];
    const float* w1 = (const float*)d_in[1];
    const float* b1 = (const float*)d_in[2];
    const float* w2 = (const float*)d_in[3];
    const float* b2 = (const float*)d_in[4];
    float* out = (float*)d_out;

    char* ws = (char*)d_ws;
    float* s_ws   = (float*)ws;
    float* gate_w = (float*)(ws + 32768);
    int*   idx_w  = (int*)(ws + 32768 + 16384);

    // trio #1
    k_mean<<<32 * NC, 64, 0, stream>>>(x, s_ws);
    k_mlp_topk<<<32, 256, 0, stream>>>(s_ws, w1, b1, w2, b2, gate_w, idx_w);
    k_gather<<<32 * NCNEW, 256, 0, stream>>>(x, gate_w, idx_w, out);
    // trio #2 — identical, idempotent; delta vs round 6 isolates
    // sum(kernel time) + 3*gap from fixed per-replay overhead.
    k_mean<<<32 * NC, 64, 0, stream>>>(x, s_ws);
    k_mlp_topk<<<32, 256, 0, stream>>>(s_ws, w1, b1, w2, b2, gate_w, idx_w);
    k_gather<<<32 * NCNEW, 256, 0, stream>>>(x, gate_w, idx_w, out);
}